// Round 1
// baseline (1784.958 us; speedup 1.0000x reference)
//
#include <hip/hip_runtime.h>
#include <math.h>

#define N_NODES 100000
#define N_EDGES 1600000
#define IN_DIM 512
#define OUT_DIM 64

// ---------------- degree ----------------
__global__ __launch_bounds__(256) void k_deg_init(float* __restrict__ deg) {
    int i = blockIdx.x * 256 + threadIdx.x;
    if (i < N_NODES) deg[i] = 1.0f;  // self-loop
}

__global__ __launch_bounds__(256) void k_deg_count(const int* __restrict__ dst,
                                                   float* __restrict__ deg) {
    int e = blockIdx.x * 256 + threadIdx.x;
    if (e < N_EDGES) atomicAdd(&deg[dst[e]], 1.0f);
}

// ---------------- h_scaled = dinv * (x @ W);  out init = h_scaled (self-loop term) ----
// 64x64 output tile per block, BK=32, 256 threads, 4x4 micro-tile per thread.
__global__ __launch_bounds__(256) void k_gemm(const float* __restrict__ x,
                                              const float* __restrict__ W,
                                              const float* __restrict__ deg,
                                              float* __restrict__ h,
                                              float* __restrict__ out) {
    __shared__ float xs[32][64];  // [kk][row]
    __shared__ float ws[32][64];  // [kk][col]
    const int t  = threadIdx.x;
    const int r0 = blockIdx.x * 64;
    const int i0 = (t >> 4) * 4;   // row offset in tile (0..60)
    const int c0 = (t & 15) * 4;   // col offset (0..60)
    const int li = t >> 3, kv = t & 7;    // x-tile load mapping
    const int lk = t >> 4, cv = t & 15;   // W-tile load mapping
    float acc[4][4] = {};

    for (int k0 = 0; k0 < IN_DIM; k0 += 32) {
#pragma unroll
        for (int pass = 0; pass < 2; ++pass) {
            int row = r0 + li + pass * 32;
            float4 v = make_float4(0.f, 0.f, 0.f, 0.f);
            if (row < N_NODES)
                v = *(const float4*)&x[row * IN_DIM + k0 + kv * 4];
            xs[kv * 4 + 0][li + pass * 32] = v.x;
            xs[kv * 4 + 1][li + pass * 32] = v.y;
            xs[kv * 4 + 2][li + pass * 32] = v.z;
            xs[kv * 4 + 3][li + pass * 32] = v.w;
            *(float4*)&ws[lk + pass * 16][cv * 4] =
                *(const float4*)&W[(k0 + lk + pass * 16) * OUT_DIM + cv * 4];
        }
        __syncthreads();
#pragma unroll
        for (int kk = 0; kk < 32; ++kk) {
            float4 a  = *(const float4*)&xs[kk][i0];
            float4 wv = *(const float4*)&ws[kk][c0];
            float av[4]  = {a.x, a.y, a.z, a.w};
            float wvv[4] = {wv.x, wv.y, wv.z, wv.w};
#pragma unroll
            for (int ii = 0; ii < 4; ++ii)
#pragma unroll
                for (int cc = 0; cc < 4; ++cc)
                    acc[ii][cc] = fmaf(av[ii], wvv[cc], acc[ii][cc]);
        }
        __syncthreads();
    }
#pragma unroll
    for (int ii = 0; ii < 4; ++ii) {
        int row = r0 + i0 + ii;
        if (row < N_NODES) {
            float dinv = rsqrtf(deg[row]);
            float4 res = make_float4(acc[ii][0] * dinv, acc[ii][1] * dinv,
                                     acc[ii][2] * dinv, acc[ii][3] * dinv);
            *(float4*)&h[row * OUT_DIM + c0]   = res;  // h_scaled
            *(float4*)&out[row * OUT_DIM + c0] = res;  // accumulator init = self-loop term
        }
    }
}

// ---------------- edge scatter: out[dst] += h_scaled[src] ----------------
// 16 threads per edge, float4 per thread -> 4 fp32 atomics.
__global__ __launch_bounds__(256) void k_scatter(const int* __restrict__ src,
                                                 const int* __restrict__ dst,
                                                 const float* __restrict__ h,
                                                 float* __restrict__ out) {
    int t  = blockIdx.x * 256 + threadIdx.x;
    int e  = t >> 4;
    int c4 = t & 15;
    if (e < N_EDGES) {
        int s = src[e], d = dst[e];
        float4 m = *(const float4*)&h[s * OUT_DIM + c4 * 4];
        float* o = &out[d * OUT_DIM + c4 * 4];
        atomicAdd(o + 0, m.x);
        atomicAdd(o + 1, m.y);
        atomicAdd(o + 2, m.z);
        atomicAdd(o + 3, m.w);
    }
}

// ---------------- finalize: out = log_softmax(dinv*acc + b) ----------------
// one wave (64 lanes) per node row; 4 nodes per block.
__global__ __launch_bounds__(256) void k_finalize(const float* __restrict__ deg,
                                                  const float* __restrict__ b,
                                                  float* __restrict__ out) {
    int node = blockIdx.x * 4 + (threadIdx.x >> 6);
    int lane = threadIdx.x & 63;
    if (node >= N_NODES) return;
    float v = out[node * OUT_DIM + lane] * rsqrtf(deg[node]) + b[lane];
    float m = v;
#pragma unroll
    for (int off = 32; off > 0; off >>= 1) m = fmaxf(m, __shfl_xor(m, off, 64));
    float ex = expf(v - m);
    float s = ex;
#pragma unroll
    for (int off = 32; off > 0; off >>= 1) s += __shfl_xor(s, off, 64);
    out[node * OUT_DIM + lane] = v - m - logf(s);
}

extern "C" void kernel_launch(void* const* d_in, const int* in_sizes, int n_in,
                              void* d_out, int out_size, void* d_ws, size_t ws_size,
                              hipStream_t stream) {
    const float* x  = (const float*)d_in[0];
    const int*   ei = (const int*)d_in[1];   // [2, E] flat: row 0 = src, row 1 = dst
    const float* W  = (const float*)d_in[2];
    const float* b  = (const float*)d_in[3];
    float* out = (float*)d_out;

    float* deg = (float*)d_ws;                           // N floats = 400000 B (16B aligned)
    float* h   = (float*)((char*)d_ws + 400000);         // N*64 floats = 25.6 MB

    const int* src = ei;
    const int* dst = ei + N_EDGES;

    k_deg_init <<<(N_NODES + 255) / 256, 256, 0, stream>>>(deg);
    k_deg_count<<<(N_EDGES + 255) / 256, 256, 0, stream>>>(dst, deg);
    k_gemm     <<<(N_NODES + 63) / 64,   256, 0, stream>>>(x, W, deg, h, out);
    k_scatter  <<<(N_EDGES * 16) / 256,  256, 0, stream>>>(src, dst, h, out);
    k_finalize <<<(N_NODES + 3) / 4,     256, 0, stream>>>(deg, b, out);
}

// Round 2
// 582.738 us; speedup vs baseline: 3.0631x; 3.0631x over previous
//
#include <hip/hip_runtime.h>
#include <math.h>

#define N_NODES 100000
#define N_EDGES 1600000
#define IN_DIM 512
#define OUT_DIM 64
#define SCAN_CHUNK 1024                      // elems per scan block
#define N_SCAN_BLOCKS ((N_NODES + SCAN_CHUNK - 1) / SCAN_CHUNK)   // 98

// ---------------- zero degree ----------------
__global__ __launch_bounds__(256) void k_zero(int* __restrict__ degi) {
    int i = blockIdx.x * 256 + threadIdx.x;
    if (i < N_NODES) degi[i] = 0;
}

// ---------------- in-degree count ----------------
__global__ __launch_bounds__(256) void k_count(const int* __restrict__ dst,
                                               int* __restrict__ degi) {
    int e = blockIdx.x * 256 + threadIdx.x;
    if (e < N_EDGES) atomicAdd(&degi[dst[e]], 1);
}

// ---------------- scan pass 1: per-1024-chunk exclusive scan ----------------
__global__ __launch_bounds__(256) void k_scan1(const int* __restrict__ degi,
                                               int* __restrict__ row_ptr,
                                               int* __restrict__ blockSums) {
    __shared__ int wsum[4];
    const int t = threadIdx.x, lane = t & 63, w = t >> 6;
    const int i = (blockIdx.x * 256 + t) * 4;
    int d[4];
#pragma unroll
    for (int j = 0; j < 4; ++j) d[j] = (i + j < N_NODES) ? degi[i + j] : 0;
    int tsum = d[0] + d[1] + d[2] + d[3];
    // inclusive wave scan of tsum
    int incl = tsum;
#pragma unroll
    for (int off = 1; off < 64; off <<= 1) {
        int v = __shfl_up(incl, off, 64);
        if (lane >= off) incl += v;
    }
    if (lane == 63) wsum[w] = incl;
    __syncthreads();
    int woff = 0;
#pragma unroll
    for (int k = 0; k < 4; ++k) if (k < w) woff += wsum[k];
    int excl = woff + incl - tsum;   // exclusive prefix of this thread's group
    if (i < N_NODES) {
        int run = excl;
#pragma unroll
        for (int j = 0; j < 4; ++j) {
            if (i + j < N_NODES) row_ptr[i + j] = run;
            run += d[j];
        }
    }
    if (t == 0) { /* nothing */ }
    __syncthreads();
    if (t == 0) blockSums[blockIdx.x] = wsum[0] + wsum[1] + wsum[2] + wsum[3];
}

// ---------------- scan pass 2: scan the 98 block sums ----------------
__global__ __launch_bounds__(128) void k_scan2(const int* __restrict__ blockSums,
                                               int* __restrict__ blockOffsets) {
    __shared__ int s[128];
    int t = threadIdx.x;
    int v = (t < N_SCAN_BLOCKS) ? blockSums[t] : 0;
    s[t] = v;
    __syncthreads();
#pragma unroll
    for (int off = 1; off < 128; off <<= 1) {
        int add = (t >= off) ? s[t - off] : 0;
        __syncthreads();
        s[t] += add;
        __syncthreads();
    }
    if (t < N_SCAN_BLOCKS) blockOffsets[t] = s[t] - v;  // exclusive
}

// ---------------- scan pass 3: add block offsets; copy to csr_pos ----------------
__global__ __launch_bounds__(256) void k_scan3(int* __restrict__ row_ptr,
                                               const int* __restrict__ blockOffsets,
                                               int* __restrict__ csr_pos) {
    int i = blockIdx.x * 256 + threadIdx.x;
    if (i < N_NODES) {
        int v = row_ptr[i] + blockOffsets[i >> 10];
        row_ptr[i] = v;
        csr_pos[i] = v;
    }
}

// ---------------- CSR fill: bucket srcs by dst ----------------
__global__ __launch_bounds__(256) void k_fill(const int* __restrict__ src,
                                              const int* __restrict__ dst,
                                              int* __restrict__ csr_pos,
                                              int* __restrict__ csr) {
    int e = blockIdx.x * 256 + threadIdx.x;
    if (e < N_EDGES) {
        int pos = atomicAdd(&csr_pos[dst[e]], 1);
        csr[pos] = src[e];
    }
}

// ---------------- h_scaled = dinv * (x @ W) ----------------
// 128x64 output tile per block, BK=32, 256 threads, 8x4 micro-tile.
__global__ __launch_bounds__(256) void k_gemm(const float* __restrict__ x,
                                              const float* __restrict__ W,
                                              const int* __restrict__ degi,
                                              float* __restrict__ h) {
    __shared__ float xs[32][128];  // [kk][row]
    __shared__ float ws[32][64];   // [kk][col]
    const int t  = threadIdx.x;
    const int r0 = blockIdx.x * 128;
    const int i0 = (t >> 4) * 8;   // row offset in tile (0..120)
    const int c0 = (t & 15) * 4;   // col offset (0..60)
    const int li = t >> 3, kv = t & 7;    // x-tile load mapping (32 rows/pass)
    const int lk = t >> 4, cv = t & 15;   // W-tile load mapping
    float acc[8][4] = {};

    for (int k0 = 0; k0 < IN_DIM; k0 += 32) {
#pragma unroll
        for (int pass = 0; pass < 4; ++pass) {
            int row = r0 + li + pass * 32;
            float4 v = make_float4(0.f, 0.f, 0.f, 0.f);
            if (row < N_NODES)
                v = *(const float4*)&x[row * IN_DIM + k0 + kv * 4];
            xs[kv * 4 + 0][li + pass * 32] = v.x;
            xs[kv * 4 + 1][li + pass * 32] = v.y;
            xs[kv * 4 + 2][li + pass * 32] = v.z;
            xs[kv * 4 + 3][li + pass * 32] = v.w;
        }
#pragma unroll
        for (int pass = 0; pass < 2; ++pass) {
            *(float4*)&ws[lk + pass * 16][cv * 4] =
                *(const float4*)&W[(k0 + lk + pass * 16) * OUT_DIM + cv * 4];
        }
        __syncthreads();
#pragma unroll
        for (int kk = 0; kk < 32; ++kk) {
            float4 a0 = *(const float4*)&xs[kk][i0];
            float4 a1 = *(const float4*)&xs[kk][i0 + 4];
            float4 wv = *(const float4*)&ws[kk][c0];
            float av[8]  = {a0.x, a0.y, a0.z, a0.w, a1.x, a1.y, a1.z, a1.w};
            float wvv[4] = {wv.x, wv.y, wv.z, wv.w};
#pragma unroll
            for (int ii = 0; ii < 8; ++ii)
#pragma unroll
                for (int cc = 0; cc < 4; ++cc)
                    acc[ii][cc] = fmaf(av[ii], wvv[cc], acc[ii][cc]);
        }
        __syncthreads();
    }
#pragma unroll
    for (int ii = 0; ii < 8; ++ii) {
        int row = r0 + i0 + ii;
        if (row < N_NODES) {
            float dinv = rsqrtf((float)(degi[row] + 1));
            float4 res = make_float4(acc[ii][0] * dinv, acc[ii][1] * dinv,
                                     acc[ii][2] * dinv, acc[ii][3] * dinv);
            *(float4*)&h[row * OUT_DIM + c0] = res;
        }
    }
}

// ---------------- gather + bias + log_softmax, one wave per node ----------------
__global__ __launch_bounds__(256) void k_gather(const int* __restrict__ degi,
                                                const int* __restrict__ row_ptr,
                                                const int* __restrict__ csr,
                                                const float* __restrict__ h,
                                                const float* __restrict__ b,
                                                float* __restrict__ out) {
    int node = blockIdx.x * 4 + (threadIdx.x >> 6);
    int lane = threadIdx.x & 63;
    if (node >= N_NODES) return;
    int cnt  = __builtin_amdgcn_readfirstlane(degi[node]);
    int base = __builtin_amdgcn_readfirstlane(row_ptr[node]);

    float acc = h[node * OUT_DIM + lane];   // self-loop term (pre-scaled)
    int e = 0;
    for (; e + 4 <= cnt; e += 4) {
        int s0 = csr[base + e + 0];
        int s1 = csr[base + e + 1];
        int s2 = csr[base + e + 2];
        int s3 = csr[base + e + 3];
        float v0 = h[s0 * OUT_DIM + lane];
        float v1 = h[s1 * OUT_DIM + lane];
        float v2 = h[s2 * OUT_DIM + lane];
        float v3 = h[s3 * OUT_DIM + lane];
        acc += v0 + v1 + v2 + v3;
    }
    for (; e < cnt; ++e)
        acc += h[csr[base + e] * OUT_DIM + lane];

    float v = acc * rsqrtf((float)(cnt + 1)) + b[lane];
    float m = v;
#pragma unroll
    for (int off = 32; off > 0; off >>= 1) m = fmaxf(m, __shfl_xor(m, off, 64));
    float ex = expf(v - m);
    float s = ex;
#pragma unroll
    for (int off = 32; off > 0; off >>= 1) s += __shfl_xor(s, off, 64);
    out[node * OUT_DIM + lane] = v - m - logf(s);
}

extern "C" void kernel_launch(void* const* d_in, const int* in_sizes, int n_in,
                              void* d_out, int out_size, void* d_ws, size_t ws_size,
                              hipStream_t stream) {
    const float* x  = (const float*)d_in[0];
    const int*   ei = (const int*)d_in[1];   // [2, E] flat: row 0 = src, row 1 = dst
    const float* W  = (const float*)d_in[2];
    const float* b  = (const float*)d_in[3];
    float* out = (float*)d_out;

    char* ws = (char*)d_ws;
    int*   degi         = (int*)(ws + 0);                 // 400,000 B
    int*   csr_pos      = (int*)(ws + 400000);            // 400,000 B
    int*   row_ptr      = (int*)(ws + 800000);            // 400,000 B
    int*   blockSums    = (int*)(ws + 1200000);           // 512 B
    int*   blockOffsets = (int*)(ws + 1200512);           // 512 B
    float* h            = (float*)(ws + 1204224);         // 25.6 MB
    int*   csr          = (int*)(ws + 26804224);          // 6.4 MB   (total ~33.2 MB)

    const int* src = ei;
    const int* dst = ei + N_EDGES;

    k_zero  <<<(N_NODES + 255) / 256, 256, 0, stream>>>(degi);
    k_count <<<(N_EDGES + 255) / 256, 256, 0, stream>>>(dst, degi);
    k_scan1 <<<N_SCAN_BLOCKS,         256, 0, stream>>>(degi, row_ptr, blockSums);
    k_scan2 <<<1,                     128, 0, stream>>>(blockSums, blockOffsets);
    k_scan3 <<<(N_NODES + 255) / 256, 256, 0, stream>>>(row_ptr, blockOffsets, csr_pos);
    k_fill  <<<(N_EDGES + 255) / 256, 256, 0, stream>>>(src, dst, csr_pos, csr);
    k_gemm  <<<(N_NODES + 127) / 128, 256, 0, stream>>>(x, W, degi, h);
    k_gather<<<(N_NODES + 3) / 4,     256, 0, stream>>>(degi, row_ptr, csr, h, b, out);
}

// Round 3
// 563.986 us; speedup vs baseline: 3.1649x; 1.0332x over previous
//
#include <hip/hip_runtime.h>
#include <math.h>

#define N_NODES 100000
#define N_EDGES 1600000
#define IN_DIM 512
#define OUT_DIM 64
#define SCAN_CHUNK 1024
#define N_SCAN_BLOCKS ((N_NODES + SCAN_CHUNK - 1) / SCAN_CHUNK)   // 98
#define N_TILES (N_NODES / 16)                                    // 6250 exact

typedef __attribute__((ext_vector_type(8))) short short8;
typedef __attribute__((ext_vector_type(4))) float float4v;

__device__ __forceinline__ unsigned short f2bf(float f) {   // RNE fp32->bf16
    unsigned int u = __float_as_uint(f);
    u += 0x7fffu + ((u >> 16) & 1u);
    return (unsigned short)(u >> 16);
}
__device__ __forceinline__ float bf2f(unsigned short s) {
    return __uint_as_float(((unsigned int)s) << 16);
}

// ---------------- zero degree ----------------
__global__ __launch_bounds__(256) void k_zero(int* __restrict__ degi) {
    int i = blockIdx.x * 256 + threadIdx.x;
    if (i < N_NODES) degi[i] = 0;
}

// ---------------- in-degree count ----------------
__global__ __launch_bounds__(256) void k_count(const int* __restrict__ dst,
                                               int* __restrict__ degi) {
    int e = blockIdx.x * 256 + threadIdx.x;
    if (e < N_EDGES) atomicAdd(&degi[dst[e]], 1);
}

// ---------------- scan pass 1 ----------------
__global__ __launch_bounds__(256) void k_scan1(const int* __restrict__ degi,
                                               int* __restrict__ row_ptr,
                                               int* __restrict__ blockSums) {
    __shared__ int wsum[4];
    const int t = threadIdx.x, lane = t & 63, w = t >> 6;
    const int i = (blockIdx.x * 256 + t) * 4;
    int d[4];
#pragma unroll
    for (int j = 0; j < 4; ++j) d[j] = (i + j < N_NODES) ? degi[i + j] : 0;
    int tsum = d[0] + d[1] + d[2] + d[3];
    int incl = tsum;
#pragma unroll
    for (int off = 1; off < 64; off <<= 1) {
        int v = __shfl_up(incl, off, 64);
        if (lane >= off) incl += v;
    }
    if (lane == 63) wsum[w] = incl;
    __syncthreads();
    int woff = 0;
#pragma unroll
    for (int k = 0; k < 4; ++k) if (k < w) woff += wsum[k];
    int excl = woff + incl - tsum;
    if (i < N_NODES) {
        int run = excl;
#pragma unroll
        for (int j = 0; j < 4; ++j) {
            if (i + j < N_NODES) row_ptr[i + j] = run;
            run += d[j];
        }
    }
    __syncthreads();
    if (t == 0) blockSums[blockIdx.x] = wsum[0] + wsum[1] + wsum[2] + wsum[3];
}

// ---------------- scan pass 2 ----------------
__global__ __launch_bounds__(128) void k_scan2(const int* __restrict__ blockSums,
                                               int* __restrict__ blockOffsets) {
    __shared__ int s[128];
    int t = threadIdx.x;
    int v = (t < N_SCAN_BLOCKS) ? blockSums[t] : 0;
    s[t] = v;
    __syncthreads();
#pragma unroll
    for (int off = 1; off < 128; off <<= 1) {
        int add = (t >= off) ? s[t - off] : 0;
        __syncthreads();
        s[t] += add;
        __syncthreads();
    }
    if (t < N_SCAN_BLOCKS) blockOffsets[t] = s[t] - v;
}

// ---------------- scan pass 3 ----------------
__global__ __launch_bounds__(256) void k_scan3(int* __restrict__ row_ptr,
                                               const int* __restrict__ blockOffsets,
                                               int* __restrict__ csr_pos) {
    int i = blockIdx.x * 256 + threadIdx.x;
    if (i < N_NODES) {
        int v = row_ptr[i] + blockOffsets[i >> 10];
        row_ptr[i] = v;
        csr_pos[i] = v;
    }
}

// ---------------- CSR fill ----------------
__global__ __launch_bounds__(256) void k_fill(const int* __restrict__ src,
                                              const int* __restrict__ dst,
                                              int* __restrict__ csr_pos,
                                              int* __restrict__ csr) {
    int e = blockIdx.x * 256 + threadIdx.x;
    if (e < N_EDGES) {
        int pos = atomicAdd(&csr_pos[dst[e]], 1);
        csr[pos] = src[e];
    }
}

// ---------------- W swizzle: fp32 [512][64] -> bf16 B-fragment order ----------------
// B frag for (kt, ct): lane holds W[kt*32 + (lane>>4)*8 + j][ct*16 + (lane&15)], j=0..7
// flat layout: Wswz[(((kt*4 + ct)*64 + lane)*8) + j]
__global__ __launch_bounds__(256) void k_wswz(const float* __restrict__ W,
                                              unsigned short* __restrict__ Wswz) {
    int t = blockIdx.x * 256 + threadIdx.x;   // 32768 elems
    if (t < IN_DIM * OUT_DIM) {
        int k = t >> 6, n = t & 63;
        int kt = k >> 5, kin = k & 31;
        int quad = kin >> 3, j = kin & 7;
        int ct = n >> 4, l16 = n & 15;
        int lane = quad * 16 + l16;
        Wswz[(((kt * 4 + ct) * 64 + lane) * 8) + j] = f2bf(W[t]);
    }
}

// ---------------- h = dinv * (x @ W), bf16 MFMA, streaming ----------------
// block = 256 thr = 4 waves; W (64 KB bf16 frags) staged in LDS once;
// each wave grid-strides over 16-row tiles of x.
__global__ __launch_bounds__(256) void k_gemm(const float* __restrict__ x,
                                              const unsigned short* __restrict__ Wswz,
                                              const int* __restrict__ degi,
                                              unsigned short* __restrict__ h) {
    __shared__ short8 Wlds[64][64];   // [kt*4+ct][lane] -> 8 bf16 = 64 KB
    const int t = threadIdx.x;
    {   // coalesced stage: 4096 x 16B chunks
        const float4v* s = (const float4v*)Wswz;
        float4v* d = (float4v*)Wlds;
        for (int i = t; i < 4096; i += 256) d[i] = s[i];
    }
    __syncthreads();

    const int lane = t & 63;
    const int quad = lane >> 4, l16 = lane & 15;
    const int gw = blockIdx.x * 4 + (t >> 6);
    const int nw = gridDim.x * 4;

    for (int tile = gw; tile < N_TILES; tile += nw) {
        const int r0 = tile * 16;
        const float* xrow = x + (size_t)(r0 + l16) * IN_DIM + quad * 8;
        // issue all 32 16B loads for this tile (deep vmcnt pipeline)
        float4v a[32];
#pragma unroll
        for (int kt = 0; kt < 16; ++kt) {
            a[kt * 2 + 0] = *(const float4v*)(xrow + kt * 32);
            a[kt * 2 + 1] = *(const float4v*)(xrow + kt * 32 + 4);
        }
        float4v acc[4] = {{0.f,0.f,0.f,0.f},{0.f,0.f,0.f,0.f},
                          {0.f,0.f,0.f,0.f},{0.f,0.f,0.f,0.f}};
#pragma unroll
        for (int kt = 0; kt < 16; ++kt) {
            union { short8 s8; unsigned short us[8]; } af;
            float4v lo = a[kt * 2], hi = a[kt * 2 + 1];
            af.us[0] = f2bf(lo.x); af.us[1] = f2bf(lo.y);
            af.us[2] = f2bf(lo.z); af.us[3] = f2bf(lo.w);
            af.us[4] = f2bf(hi.x); af.us[5] = f2bf(hi.y);
            af.us[6] = f2bf(hi.z); af.us[7] = f2bf(hi.w);
#pragma unroll
            for (int ct = 0; ct < 4; ++ct) {
                short8 bf = Wlds[kt * 4 + ct][lane];
                acc[ct] = __builtin_amdgcn_mfma_f32_16x16x32_bf16(af.s8, bf, acc[ct], 0, 0, 0);
            }
        }
        // epilogue: C layout col=lane&15, row=quad*4+reg
#pragma unroll
        for (int reg = 0; reg < 4; ++reg) {
            int orow = r0 + quad * 4 + reg;
            float dinv = rsqrtf((float)(degi[orow] + 1));
#pragma unroll
            for (int ct = 0; ct < 4; ++ct)
                h[(size_t)orow * OUT_DIM + ct * 16 + l16] = f2bf(acc[ct][reg] * dinv);
        }
    }
}

// ---------------- gather + bias + log_softmax, one wave per node ----------------
__global__ __launch_bounds__(256) void k_gather(const int* __restrict__ degi,
                                                const int* __restrict__ row_ptr,
                                                const int* __restrict__ csr,
                                                const unsigned short* __restrict__ h,
                                                const float* __restrict__ b,
                                                float* __restrict__ out) {
    int node = blockIdx.x * 4 + (threadIdx.x >> 6);
    int lane = threadIdx.x & 63;
    if (node >= N_NODES) return;
    int cnt  = __builtin_amdgcn_readfirstlane(degi[node]);
    int base = __builtin_amdgcn_readfirstlane(row_ptr[node]);

    float acc = bf2f(h[(size_t)node * OUT_DIM + lane]);   // self-loop term
    int e = 0;
    for (; e + 8 <= cnt; e += 8) {
        int s0 = csr[base + e + 0], s1 = csr[base + e + 1];
        int s2 = csr[base + e + 2], s3 = csr[base + e + 3];
        int s4 = csr[base + e + 4], s5 = csr[base + e + 5];
        int s6 = csr[base + e + 6], s7 = csr[base + e + 7];
        float v0 = bf2f(h[(size_t)s0 * OUT_DIM + lane]);
        float v1 = bf2f(h[(size_t)s1 * OUT_DIM + lane]);
        float v2 = bf2f(h[(size_t)s2 * OUT_DIM + lane]);
        float v3 = bf2f(h[(size_t)s3 * OUT_DIM + lane]);
        float v4 = bf2f(h[(size_t)s4 * OUT_DIM + lane]);
        float v5 = bf2f(h[(size_t)s5 * OUT_DIM + lane]);
        float v6 = bf2f(h[(size_t)s6 * OUT_DIM + lane]);
        float v7 = bf2f(h[(size_t)s7 * OUT_DIM + lane]);
        acc += ((v0 + v1) + (v2 + v3)) + ((v4 + v5) + (v6 + v7));
    }
    for (; e < cnt; ++e)
        acc += bf2f(h[(size_t)csr[base + e] * OUT_DIM + lane]);

    float v = acc * rsqrtf((float)(cnt + 1)) + b[lane];
    float m = v;
#pragma unroll
    for (int off = 32; off > 0; off >>= 1) m = fmaxf(m, __shfl_xor(m, off, 64));
    float ex = expf(v - m);
    float s = ex;
#pragma unroll
    for (int off = 32; off > 0; off >>= 1) s += __shfl_xor(s, off, 64);
    out[(size_t)node * OUT_DIM + lane] = v - m - logf(s);
}

extern "C" void kernel_launch(void* const* d_in, const int* in_sizes, int n_in,
                              void* d_out, int out_size, void* d_ws, size_t ws_size,
                              hipStream_t stream) {
    const float* x  = (const float*)d_in[0];
    const int*   ei = (const int*)d_in[1];   // [2, E]: row 0 = src, row 1 = dst
    const float* W  = (const float*)d_in[2];
    const float* b  = (const float*)d_in[3];
    float* out = (float*)d_out;

    char* ws = (char*)d_ws;
    int*            degi         = (int*)(ws + 0);            // 400,000 B
    int*            csr_pos      = (int*)(ws + 400000);       // 400,000 B
    int*            row_ptr      = (int*)(ws + 800000);       // 400,000 B
    int*            blockSums    = (int*)(ws + 1200000);      // 512 B
    int*            blockOffsets = (int*)(ws + 1200512);      // 512 B
    unsigned short* Wswz         = (unsigned short*)(ws + 1201024);  // 65,536 B
    unsigned short* h            = (unsigned short*)(ws + 1266560);  // 12.8 MB (16B aligned)
    int*            csr          = (int*)(ws + 14066560);     // 6.4 MB  (total ~20.5 MB)

    const int* src = ei;
    const int* dst = ei + N_EDGES;

    k_zero  <<<(N_NODES + 255) / 256, 256, 0, stream>>>(degi);
    k_count <<<(N_EDGES + 255) / 256, 256, 0, stream>>>(dst, degi);
    k_scan1 <<<N_SCAN_BLOCKS,         256, 0, stream>>>(degi, row_ptr, blockSums);
    k_scan2 <<<1,                     128, 0, stream>>>(blockSums, blockOffsets);
    k_scan3 <<<(N_NODES + 255) / 256, 256, 0, stream>>>(row_ptr, blockOffsets, csr_pos);
    k_fill  <<<(N_EDGES + 255) / 256, 256, 0, stream>>>(src, dst, csr_pos, csr);
    k_wswz  <<<(IN_DIM * OUT_DIM + 255) / 256, 256, 0, stream>>>(W, Wswz);
    k_gemm  <<<512,                   256, 0, stream>>>(x, Wswz, degi, h);
    k_gather<<<(N_NODES + 3) / 4,     256, 0, stream>>>(degi, row_ptr, csr, h, b, out);
}

// Round 4
// 484.502 us; speedup vs baseline: 3.6841x; 1.1641x over previous
//
#include <hip/hip_runtime.h>
#include <math.h>

#define N_NODES 100000
#define N_EDGES 1600000
#define IN_DIM 512
#define OUT_DIM 64
#define NB 1024                    // sort buckets (dst>>7)
#define NPB 128                    // partition blocks
#define CHUNK (N_EDGES / NPB)      // 12500 edges per partition block (exact)
#define N_BUCKETS_USED 782         // ceil(100000/128)
#define N_TILES (N_NODES / 16)     // 6250 exact

typedef __attribute__((ext_vector_type(8))) short short8;
typedef __attribute__((ext_vector_type(4))) float float4v;

__device__ __forceinline__ unsigned short f2bf(float f) {   // RNE fp32->bf16
    unsigned int u = __float_as_uint(f);
    u += 0x7fffu + ((u >> 16) & 1u);
    return (unsigned short)(u >> 16);
}
__device__ __forceinline__ float bf2f(unsigned short s) {
    return __uint_as_float(((unsigned int)s) << 16);
}

// ---------------- pass 1: per-block bucket histogram ----------------
__global__ __launch_bounds__(256) void k_hist1(const int* __restrict__ dst,
                                               int* __restrict__ blockHist) {
    __shared__ int hist[NB];
    const int t = threadIdx.x, b = blockIdx.x;
    for (int k = t; k < NB; k += 256) hist[k] = 0;
    __syncthreads();
    const int e0 = b * CHUNK;
    for (int i = t; i < CHUNK; i += 256)
        atomicAdd(&hist[dst[e0 + i] >> 7], 1);
    __syncthreads();
    for (int k = t; k < NB; k += 256) blockHist[b * NB + k] = hist[k];
}

// ---------------- pass 2: bucket bases + per-(block,bucket) starts ----------------
__global__ __launch_bounds__(256) void k_offsets(const int* __restrict__ blockHist,
                                                 int* __restrict__ blockStart,
                                                 int* __restrict__ bucketBase) {
    __shared__ int colsum[NB];
    __shared__ int bbase[NB + 1];
    __shared__ int wtot[4];
    const int t = threadIdx.x, lane = t & 63, w = t >> 6;
    for (int k = t; k < NB; k += 256) {
        int s = 0;
        for (int b = 0; b < NPB; ++b) s += blockHist[b * NB + k];
        colsum[k] = s;
    }
    __syncthreads();
    int c0 = colsum[t * 4 + 0], c1 = colsum[t * 4 + 1];
    int c2 = colsum[t * 4 + 2], c3 = colsum[t * 4 + 3];
    int tsum = c0 + c1 + c2 + c3;
    int incl = tsum;
#pragma unroll
    for (int off = 1; off < 64; off <<= 1) {
        int u = __shfl_up(incl, off, 64);
        if (lane >= off) incl += u;
    }
    if (lane == 63) wtot[w] = incl;
    __syncthreads();
    int woff = 0;
#pragma unroll
    for (int k2 = 0; k2 < 4; ++k2) if (k2 < w) woff += wtot[k2];
    int excl = woff + incl - tsum;
    bbase[t * 4 + 0] = excl;
    bbase[t * 4 + 1] = excl + c0;
    bbase[t * 4 + 2] = excl + c0 + c1;
    bbase[t * 4 + 3] = excl + c0 + c1 + c2;
    if (t == 255) bbase[NB] = excl + tsum;   // == N_EDGES
    __syncthreads();
    for (int k = t; k < NB + 1; k += 256) bucketBase[k] = bbase[k];
    for (int k = t; k < NB; k += 256) {
        int run = bbase[k];
        for (int b = 0; b < NPB; ++b) {
            blockStart[b * NB + k] = run;
            run += blockHist[b * NB + k];
        }
    }
}

// ---------------- pass 3: partition edges into buckets (packed codes) ----------------
__global__ __launch_bounds__(256) void k_partition(const int* __restrict__ dst,
                                                   const int* __restrict__ src,
                                                   const int* __restrict__ blockStart,
                                                   int* __restrict__ parts) {
    __shared__ int cursor[NB];
    const int t = threadIdx.x, b = blockIdx.x;
    for (int k = t; k < NB; k += 256) cursor[k] = blockStart[b * NB + k];
    __syncthreads();
    const int e0 = b * CHUNK;
    for (int i = t; i < CHUNK; i += 256) {
        int d = dst[e0 + i];
        int s = src[e0 + i];
        int k = d >> 7;
        int pos = atomicAdd(&cursor[k], 1);          // LDS atomic (fast)
        parts[pos] = ((d & 127) << 17) | s;           // src < 2^17
    }
}

// ---------------- pass 4: per-bucket counting sort -> deg, row_ptr, csr ----------------
__global__ __launch_bounds__(256) void k_bucket(const int* __restrict__ parts,
                                                const int* __restrict__ bucketBase,
                                                int* __restrict__ degi,
                                                int* __restrict__ row_ptr,
                                                int* __restrict__ csr) {
    __shared__ int cnt[128];
    __shared__ int cur[128];
    __shared__ int wtot[2];
    const int t = threadIdx.x, k = blockIdx.x;
    const int base = bucketBase[k];
    const int n    = bucketBase[k + 1] - base;
    if (t < 128) cnt[t] = 0;
    __syncthreads();
    for (int i = t; i < n; i += 256)
        atomicAdd(&cnt[parts[base + i] >> 17], 1);
    __syncthreads();
    int incl = 0, v = 0;
    if (t < 128) {
        int lane = t & 63;
        v = cnt[t];
        incl = v;
#pragma unroll
        for (int off = 1; off < 64; off <<= 1) {
            int u = __shfl_up(incl, off, 64);
            if (lane >= off) incl += u;
        }
        if (lane == 63) wtot[t >> 6] = incl;
    }
    __syncthreads();
    if (t < 128) {
        int excl = incl - v + ((t >> 6) ? wtot[0] : 0);
        cur[t] = excl;
        int node = k * 128 + t;
        if (node < N_NODES) {
            degi[node]    = v;
            row_ptr[node] = base + excl;
        }
    }
    __syncthreads();
    for (int i = t; i < n; i += 256) {
        int code = parts[base + i];
        int nl = code >> 17, s = code & 0x1FFFF;
        int pos = atomicAdd(&cur[nl], 1);            // LDS atomic
        csr[base + pos] = s;                         // contiguous ~8KB region, L2-resident
    }
}

// ---------------- W swizzle: fp32 [512][64] -> bf16 B-fragment order ----------------
__global__ __launch_bounds__(256) void k_wswz(const float* __restrict__ W,
                                              unsigned short* __restrict__ Wswz) {
    int t = blockIdx.x * 256 + threadIdx.x;
    if (t < IN_DIM * OUT_DIM) {
        int k = t >> 6, n = t & 63;
        int kt = k >> 5, kin = k & 31;
        int quad = kin >> 3, j = kin & 7;
        int ct = n >> 4, l16 = n & 15;
        int lane = quad * 16 + l16;
        Wswz[(((kt * 4 + ct) * 64 + lane) * 8) + j] = f2bf(W[t]);
    }
}

// ---------------- h = dinv * (x @ W), bf16 MFMA, streaming ----------------
__global__ __launch_bounds__(256) void k_gemm(const float* __restrict__ x,
                                              const unsigned short* __restrict__ Wswz,
                                              const int* __restrict__ degi,
                                              unsigned short* __restrict__ h) {
    __shared__ short8 Wlds[64][64];   // 64 KB
    const int t = threadIdx.x;
    {
        const float4v* s = (const float4v*)Wswz;
        float4v* d = (float4v*)Wlds;
        for (int i = t; i < 4096; i += 256) d[i] = s[i];
    }
    __syncthreads();

    const int lane = t & 63;
    const int quad = lane >> 4, l16 = lane & 15;
    const int gw = blockIdx.x * 4 + (t >> 6);
    const int nw = gridDim.x * 4;

    for (int tile = gw; tile < N_TILES; tile += nw) {
        const int r0 = tile * 16;
        const float* xrow = x + (size_t)(r0 + l16) * IN_DIM + quad * 8;
        float4v a[32];
#pragma unroll
        for (int kt = 0; kt < 16; ++kt) {
            a[kt * 2 + 0] = *(const float4v*)(xrow + kt * 32);
            a[kt * 2 + 1] = *(const float4v*)(xrow + kt * 32 + 4);
        }
        float4v acc[4] = {{0.f,0.f,0.f,0.f},{0.f,0.f,0.f,0.f},
                          {0.f,0.f,0.f,0.f},{0.f,0.f,0.f,0.f}};
#pragma unroll
        for (int kt = 0; kt < 16; ++kt) {
            union { short8 s8; unsigned short us[8]; } af;
            float4v lo = a[kt * 2], hi = a[kt * 2 + 1];
            af.us[0] = f2bf(lo.x); af.us[1] = f2bf(lo.y);
            af.us[2] = f2bf(lo.z); af.us[3] = f2bf(lo.w);
            af.us[4] = f2bf(hi.x); af.us[5] = f2bf(hi.y);
            af.us[6] = f2bf(hi.z); af.us[7] = f2bf(hi.w);
#pragma unroll
            for (int ct = 0; ct < 4; ++ct) {
                short8 bf = Wlds[kt * 4 + ct][lane];
                acc[ct] = __builtin_amdgcn_mfma_f32_16x16x32_bf16(af.s8, bf, acc[ct], 0, 0, 0);
            }
        }
#pragma unroll
        for (int reg = 0; reg < 4; ++reg) {
            int orow = r0 + quad * 4 + reg;
            float dinv = rsqrtf((float)(degi[orow] + 1));
#pragma unroll
            for (int ct = 0; ct < 4; ++ct)
                h[(size_t)orow * OUT_DIM + ct * 16 + l16] = f2bf(acc[ct][reg] * dinv);
        }
    }
}

// ---------------- gather + bias + log_softmax, one wave per node ----------------
__global__ __launch_bounds__(256) void k_gather(const int* __restrict__ degi,
                                                const int* __restrict__ row_ptr,
                                                const int* __restrict__ csr,
                                                const unsigned short* __restrict__ h,
                                                const float* __restrict__ b,
                                                float* __restrict__ out) {
    int node = blockIdx.x * 4 + (threadIdx.x >> 6);
    int lane = threadIdx.x & 63;
    if (node >= N_NODES) return;
    int cnt  = __builtin_amdgcn_readfirstlane(degi[node]);
    int base = __builtin_amdgcn_readfirstlane(row_ptr[node]);

    float acc = bf2f(h[(size_t)node * OUT_DIM + lane]);
    int e = 0;
    for (; e + 8 <= cnt; e += 8) {
        int s0 = csr[base + e + 0], s1 = csr[base + e + 1];
        int s2 = csr[base + e + 2], s3 = csr[base + e + 3];
        int s4 = csr[base + e + 4], s5 = csr[base + e + 5];
        int s6 = csr[base + e + 6], s7 = csr[base + e + 7];
        float v0 = bf2f(h[(size_t)s0 * OUT_DIM + lane]);
        float v1 = bf2f(h[(size_t)s1 * OUT_DIM + lane]);
        float v2 = bf2f(h[(size_t)s2 * OUT_DIM + lane]);
        float v3 = bf2f(h[(size_t)s3 * OUT_DIM + lane]);
        float v4 = bf2f(h[(size_t)s4 * OUT_DIM + lane]);
        float v5 = bf2f(h[(size_t)s5 * OUT_DIM + lane]);
        float v6 = bf2f(h[(size_t)s6 * OUT_DIM + lane]);
        float v7 = bf2f(h[(size_t)s7 * OUT_DIM + lane]);
        acc += ((v0 + v1) + (v2 + v3)) + ((v4 + v5) + (v6 + v7));
    }
    for (; e < cnt; ++e)
        acc += bf2f(h[(size_t)csr[base + e] * OUT_DIM + lane]);

    float v = acc * rsqrtf((float)(cnt + 1)) + b[lane];
    float m = v;
#pragma unroll
    for (int off = 32; off > 0; off >>= 1) m = fmaxf(m, __shfl_xor(m, off, 64));
    float ex = expf(v - m);
    float s = ex;
#pragma unroll
    for (int off = 32; off > 0; off >>= 1) s += __shfl_xor(s, off, 64);
    out[(size_t)node * OUT_DIM + lane] = v - m - logf(s);
}

extern "C" void kernel_launch(void* const* d_in, const int* in_sizes, int n_in,
                              void* d_out, int out_size, void* d_ws, size_t ws_size,
                              hipStream_t stream) {
    const float* x  = (const float*)d_in[0];
    const int*   ei = (const int*)d_in[1];   // [2, E]: row 0 = src, row 1 = dst
    const float* W  = (const float*)d_in[2];
    const float* b  = (const float*)d_in[3];
    float* out = (float*)d_out;

    char* ws = (char*)d_ws;
    int*            degi       = (int*)(ws + 0);              // 400,000 B
    int*            row_ptr    = (int*)(ws + 400000);         // 400,000 B
    int*            blockHist  = (int*)(ws + 800000);         // 524,288 B
    int*            blockStart = (int*)(ws + 1324288);        // 524,288 B
    int*            bucketBase = (int*)(ws + 1848576);        // 4,100 B (pad to 4,352)
    unsigned short* Wswz       = (unsigned short*)(ws + 1852928);   // 65,536 B
    unsigned short* h          = (unsigned short*)(ws + 1918464);   // 12,800,000 B
    int*            parts      = (int*)(ws + 14718464);       // 6,400,000 B
    int*            csr        = (int*)(ws + 21118464);       // 6,400,000 B  (~27.5 MB total)

    const int* src = ei;
    const int* dst = ei + N_EDGES;

    k_hist1    <<<NPB, 256, 0, stream>>>(dst, blockHist);
    k_offsets  <<<1,   256, 0, stream>>>(blockHist, blockStart, bucketBase);
    k_partition<<<NPB, 256, 0, stream>>>(dst, src, blockStart, parts);
    k_bucket   <<<N_BUCKETS_USED, 256, 0, stream>>>(parts, bucketBase, degi, row_ptr, csr);
    k_wswz     <<<(IN_DIM * OUT_DIM + 255) / 256, 256, 0, stream>>>(W, Wswz);
    k_gemm     <<<512, 256, 0, stream>>>(x, Wswz, degi, h);
    k_gather   <<<(N_NODES + 3) / 4, 256, 0, stream>>>(degi, row_ptr, csr, h, b, out);
}